// Round 2
// baseline (590.601 us; speedup 1.0000x reference)
//
#include <hip/hip_runtime.h>
#include <hip/hip_bf16.h>

#define VOCAB 12149
#define EMB 50
#define TAGS 9
#define HID 128
#define START_TOK 7
#define BSZ 256
#define TLEN 512

__device__ __forceinline__ float tanh_fast(float x) {
  // tanh(x) = 1 - 2/(exp(2x)+1); exact identity, native exp+rcp.
  float e = __expf(2.0f * x);
  return 1.0f - 2.0f * __builtin_amdgcn_rcpf(e + 1.0f);
}

// exw[v][j] = sum_e emb[v][e] * enc_Wx[e][j] + enc_b[j]
__global__ __launch_bounds__(128) void exw_kernel(
    const float* __restrict__ emb, const float* __restrict__ Wx,
    const float* __restrict__ bv, float* __restrict__ exw)
{
  __shared__ float wx_s[EMB * HID];
  __shared__ float emb_s[8 * EMB];
  const int tid = threadIdx.x;
  const int v0 = blockIdx.x * 8;
  for (int idx = tid; idx < EMB * HID; idx += 128) wx_s[idx] = Wx[idx];
  for (int idx = tid; idx < 8 * EMB; idx += 128) {
    int r = idx / EMB;
    int e = idx - r * EMB;
    int v = v0 + r;
    emb_s[idx] = (v < VOCAB) ? emb[v * EMB + e] : 0.0f;
  }
  __syncthreads();
  const float bj = bv[tid];
  for (int r = 0; r < 8; ++r) {
    int v = v0 + r;
    if (v >= VOCAB) break;
    float acc = bj;
#pragma unroll
    for (int e = 0; e < EMB; ++e) acc += emb_s[r * EMB + e] * wx_s[e * HID + tid];
    exw[v * HID + tid] = acc;
  }
}

// One workgroup (256 threads, 4 waves) per batch row.
// Thread i -> (j = i>>1, q = i&1). Lane holds Wh[q*64+kk][j], kk=0..63.
__global__ __launch_bounds__(256) void rnn_kernel(
    const int* __restrict__ inputs, const int* __restrict__ labels,
    const float* __restrict__ exw,
    const float* __restrict__ encWh,
    const float* __restrict__ dembG, const float* __restrict__ decWx,
    const float* __restrict__ decWh, const float* __restrict__ decb,
    const float* __restrict__ W, const float* __restrict__ bout,
    float* __restrict__ out)
{
  __shared__ float h_s[2][HID];
  __shared__ int tok_s[TLEN];
  __shared__ int lab_s[TLEN];
  __shared__ float dxw_s[TAGS * HID];
  __shared__ float demb_s[TAGS * EMB];

  const int i = threadIdx.x;     // 0..255
  const int j = i >> 1;          // 0..127
  const int q = i & 1;           // 0..1
  const int bidx = blockIdx.x;

  // ---- stage token/label streams + decoder embedding ----
  tok_s[i] = inputs[bidx * TLEN + i];
  tok_s[i + 256] = inputs[bidx * TLEN + i + 256];
  lab_s[i] = labels[bidx * TLEN + i];
  lab_s[i + 256] = labels[bidx * TLEN + i + 256];
  for (int idx = i; idx < TAGS * EMB; idx += 256) demb_s[idx] = dembG[idx];
  if (i < HID) h_s[0][i] = 0.0f;

  // ---- encoder Wh into registers: wh[kk] = encWh[(q*64+kk)][j] ----
  float wh[64];
#pragma unroll
  for (int kk = 0; kk < 64; ++kk) wh[kk] = encWh[(q * 64 + kk) * HID + j];

  // ---- output-projection registers: 16-lane groups, oo = i>>4, part = i&15 ----
  const int oo = i >> 4;         // 0..15 (only 0..8 active)
  const int part = i & 15;
  float wp[8];
  float bo = 0.0f;
#pragma unroll
  for (int u = 0; u < 8; ++u) wp[u] = 0.0f;
  if (oo < TAGS) {
#pragma unroll
    for (int u = 0; u < 8; ++u) wp[u] = W[(part * 8 + u) * TAGS + oo];
    bo = bout[oo];
  }
  __syncthreads();

  // ---- dxw[tag][j2] = dec_emb[tag] @ dec_Wx + dec_b ----
  for (int task = i; task < TAGS * HID; task += 256) {
    int tag = task >> 7;
    int j2 = task & 127;
    float acc = decb[j2];
#pragma unroll
    for (int e = 0; e < EMB; ++e) acc += demb_s[tag * EMB + e] * decWx[e * HID + j2];
    dxw_s[task] = acc;
  }
  __syncthreads();

  const float* exw_j = exw + j;
  int cur = 0;

  // ======== encoder: h = tanh(exw[tok] + h @ Wh_enc) ========
  float xv0 = exw_j[tok_s[0] * HID];
  float xv1 = exw_j[tok_s[1] * HID];
  float xv2 = exw_j[tok_s[2] * HID];
  for (int t = 0; t < TLEN; ++t) {
    int tn = (t + 3 < TLEN) ? (t + 3) : (TLEN - 1);
    float xvn = exw_j[tok_s[tn] * HID];   // prefetch 3 ahead

    float a0 = (q == 0) ? xv0 : 0.0f;
    float a1 = 0.0f, a2 = 0.0f, a3 = 0.0f;
    const float4* h4 = (const float4*)(&h_s[cur][q * 64]);
#pragma unroll
    for (int kk = 0; kk < 16; ++kk) {
      float4 hv = h4[kk];
      a0 += hv.x * wh[kk * 4 + 0];
      a1 += hv.y * wh[kk * 4 + 1];
      a2 += hv.z * wh[kk * 4 + 2];
      a3 += hv.w * wh[kk * 4 + 3];
    }
    float s = (a0 + a1) + (a2 + a3);
    s += __shfl_xor(s, 1);
    float hnew = tanh_fast(s);
    if (q == 0) h_s[cur ^ 1][j] = hnew;
    __syncthreads();
    cur ^= 1;
    xv0 = xv1; xv1 = xv2; xv2 = xvn;
  }

  // ---- swap in decoder Wh (reuses the same registers) ----
#pragma unroll
  for (int kk = 0; kk < 64; ++kk) wh[kk] = decWh[(q * 64 + kk) * HID + j];

  // ======== decoder: h = tanh(dxw[lab] + h @ Wh_dec); out = h @ W + b ========
  for (int t = 0; t < TLEN; ++t) {
    int lab = (t == 0) ? START_TOK : lab_s[t - 1];
    float xv = dxw_s[lab * HID + j];

    float a0 = (q == 0) ? xv : 0.0f;
    float a1 = 0.0f, a2 = 0.0f, a3 = 0.0f;
    const float4* h4 = (const float4*)(&h_s[cur][q * 64]);
#pragma unroll
    for (int kk = 0; kk < 16; ++kk) {
      float4 hv = h4[kk];
      a0 += hv.x * wh[kk * 4 + 0];
      a1 += hv.y * wh[kk * 4 + 1];
      a2 += hv.z * wh[kk * 4 + 2];
      a3 += hv.w * wh[kk * 4 + 3];
    }
    float s = (a0 + a1) + (a2 + a3);
    s += __shfl_xor(s, 1);
    float hnew = tanh_fast(s);
    if (q == 0) h_s[cur ^ 1][j] = hnew;
    __syncthreads();

    // fused output projection on the just-published buffer (overlaps next step)
    if (oo < TAGS) {
      const float4* hp = (const float4*)(&h_s[cur ^ 1][part * 8]);
      float4 u0 = hp[0];
      float4 u1 = hp[1];
      float p = u0.x * wp[0] + u0.y * wp[1] + u0.z * wp[2] + u0.w * wp[3]
              + u1.x * wp[4] + u1.y * wp[5] + u1.z * wp[6] + u1.w * wp[7];
      p += __shfl_xor(p, 1);
      p += __shfl_xor(p, 2);
      p += __shfl_xor(p, 4);
      p += __shfl_xor(p, 8);
      if (part == 0) out[(bidx * TLEN + t) * TAGS + oo] = p + bo;
    }
    cur ^= 1;
  }
}

extern "C" void kernel_launch(void* const* d_in, const int* in_sizes, int n_in,
                              void* d_out, int out_size, void* d_ws, size_t ws_size,
                              hipStream_t stream) {
  const int* inputs   = (const int*)d_in[0];
  const int* labels   = (const int*)d_in[1];
  const float* emb    = (const float*)d_in[2];
  const float* encWx  = (const float*)d_in[3];
  const float* encWh  = (const float*)d_in[4];
  const float* encb   = (const float*)d_in[5];
  const float* demb   = (const float*)d_in[6];
  const float* decWx  = (const float*)d_in[7];
  const float* decWh  = (const float*)d_in[8];
  const float* decb   = (const float*)d_in[9];
  const float* W      = (const float*)d_in[10];
  const float* bo     = (const float*)d_in[11];
  float* out = (float*)d_out;

  float* exw = (float*)d_ws;  // VOCAB*HID floats = 6.22 MB

  exw_kernel<<<(VOCAB + 7) / 8, 128, 0, stream>>>(emb, encWx, encb, exw);
  rnn_kernel<<<BSZ, 256, 0, stream>>>(inputs, labels, exw, encWh,
                                      demb, decWx, decWh, decb, W, bo, out);
}

// Round 3
// 360.370 us; speedup vs baseline: 1.6389x; 1.6389x over previous
//
#include <hip/hip_runtime.h>
#include <hip/hip_bf16.h>

#define VOCAB 12149
#define EMB 50
#define TAGS 9
#define HID 128
#define START_TOK 7
#define BSZ 256
#define TLEN 512

__device__ __forceinline__ float tanh_fast(float x) {
  // tanh(x) = 1 - 2/(exp(2x)+1); native exp+rcp.
  float e = __expf(2.0f * x);
  return 1.0f - 2.0f * __builtin_amdgcn_rcpf(e + 1.0f);
}

// DPP cross-lane move (VALU pipe — keeps reductions off the LDS pipe)
template<int CTRL>
__device__ __forceinline__ float dpp_mov(float x) {
  return __int_as_float(__builtin_amdgcn_update_dpp(
      0, __float_as_int(x), CTRL, 0xF, 0xF, true));
}
#define DPP_XOR1 0xB1         // quad_perm [1,0,3,2]
#define DPP_XOR2 0x4E         // quad_perm [2,3,0,1]
#define DPP_HALF_MIRROR 0x141 // lane -> lane^7 within 8 (valid xor4 after quad reduce)
#define DPP_MIRROR 0x140      // lane -> 15-lane within 16 (valid xor8 after xor4)

// exw[v][j] = sum_e emb[v][e] * enc_Wx[e][j] + enc_b[j]
__global__ __launch_bounds__(128) void exw_kernel(
    const float* __restrict__ emb, const float* __restrict__ Wx,
    const float* __restrict__ bv, float* __restrict__ exw)
{
  __shared__ float wx_s[EMB * HID];
  __shared__ float emb_s[8 * EMB];
  const int tid = threadIdx.x;
  const int v0 = blockIdx.x * 8;
  for (int idx = tid; idx < EMB * HID; idx += 128) wx_s[idx] = Wx[idx];
  for (int idx = tid; idx < 8 * EMB; idx += 128) {
    int r = idx / EMB;
    int e = idx - r * EMB;
    int v = v0 + r;
    emb_s[idx] = (v < VOCAB) ? emb[v * EMB + e] : 0.0f;
  }
  __syncthreads();
  const float bj = bv[tid];
  for (int r = 0; r < 8; ++r) {
    int v = v0 + r;
    if (v >= VOCAB) break;
    float acc = bj;
#pragma unroll
    for (int e = 0; e < EMB; ++e) acc += emb_s[r * EMB + e] * wx_s[e * HID + tid];
    exw[v * HID + tid] = acc;
  }
}

// One workgroup (256 thr, 4 waves) per batch row.
// lane -> q = lane&3 (k-split of 32), jj = lane>>2 (output pair w*32+jj*2).
// Each h float4 read feeds 2 outputs -> 8 ds_read_b128/lane, 32/CU/step.
__global__ __launch_bounds__(256) void rnn_kernel(
    const int* __restrict__ inputs, const int* __restrict__ labels,
    const float* __restrict__ exw,
    const float* __restrict__ encWh,
    const float* __restrict__ dembG, const float* __restrict__ decWx,
    const float* __restrict__ decWh, const float* __restrict__ decb,
    const float* __restrict__ W, const float* __restrict__ bout,
    float* __restrict__ out)
{
  __shared__ float h_s[2][HID];
  __shared__ int tok_s[TLEN];
  __shared__ int lab_s[TLEN];
  __shared__ float dxw_s[TAGS * HID];
  __shared__ float demb_s[TAGS * EMB];

  const int i = threadIdx.x;       // 0..255
  const int w = i >> 6;            // wave 0..3
  const int lane = i & 63;
  const int q = lane & 3;          // k-split
  const int jj = lane >> 2;        // 0..15
  const int jbase = w * 32 + jj * 2;
  const int jout = jbase + (q & 1);
  const int bidx = blockIdx.x;

  tok_s[i] = inputs[bidx * TLEN + i];
  tok_s[i + 256] = inputs[bidx * TLEN + 256 + i];
  lab_s[i] = labels[bidx * TLEN + i];
  lab_s[i + 256] = labels[bidx * TLEN + 256 + i];
  for (int idx = i; idx < TAGS * EMB; idx += 256) demb_s[idx] = dembG[idx];
  if (i < HID) h_s[0][i] = 0.0f;

  // Weight regs, slot-rotated so LDS reads are bank-conflict-free with
  // static register indices: slot r,c  <->  k = q*32 + ((r+2q)&7)*4 + c.
  float2 wv[32];
#pragma unroll
  for (int r = 0; r < 8; ++r) {
    const int kb = q * 32 + ((r + 2 * q) & 7) * 4;
#pragma unroll
    for (int c = 0; c < 4; ++c)
      wv[r * 4 + c] = *(const float2*)(&encWh[(kb + c) * HID + jbase]);
  }

  // Output projection: 16-lane groups; slot-staggered reads (2-way max).
  const int oo = i >> 4;           // 0..15 (active < 9)
  const int part = i & 15;
  const int s0 = (part >> 2) & 1;
  float wp[8];
  float bo = 0.0f;
#pragma unroll
  for (int u = 0; u < 8; ++u) wp[u] = 0.0f;
  if (oo < TAGS) {
#pragma unroll
    for (int s = 0; s < 2; ++s)
#pragma unroll
      for (int c = 0; c < 4; ++c)
        wp[s * 4 + c] = W[(part * 8 + (s ^ s0) * 4 + c) * TAGS + oo];
    bo = bout[oo];
  }
  __syncthreads();

  // dxw[tag][j] = dec_emb[tag] @ dec_Wx + dec_b
  for (int task = i; task < TAGS * HID; task += 256) {
    int tag = task >> 7;
    int j2 = task & 127;
    float acc = decb[j2];
#pragma unroll
    for (int e = 0; e < EMB; ++e) acc += demb_s[tag * EMB + e] * decWx[e * HID + j2];
    dxw_s[task] = acc;
  }
  __syncthreads();

  const float* exw_j = exw + jout;
  const bool odd = (q & 1) != 0;
  int cur = 0;

  float xv0 = exw_j[tok_s[0] * HID];
  float xv1 = exw_j[tok_s[1] * HID];
  float xv2 = exw_j[tok_s[2] * HID];
  float xv3 = exw_j[tok_s[3] * HID];

  // ======== encoder ========
#pragma unroll 4
  for (int t = 0; t < TLEN; ++t) {
    int tn = (t + 4 < TLEN) ? t + 4 : TLEN - 1;
    float xvn = exw_j[tok_s[tn] * HID];   // prefetch 4 ahead (renamed via unroll)

    const float4* h4 = (const float4*)(h_s[cur]) + q * 8;
    float a0x = 0, a0y = 0, a1x = 0, a1y = 0;
#pragma unroll
    for (int r = 0; r < 8; ++r) {
      float4 hv = h4[(r + 2 * q) & 7];
      float2 w0 = wv[r * 4 + 0], w1 = wv[r * 4 + 1];
      float2 w2 = wv[r * 4 + 2], w3 = wv[r * 4 + 3];
      a0x += hv.x * w0.x; a0y += hv.y * w1.x; a0x += hv.z * w2.x; a0y += hv.w * w3.x;
      a1x += hv.x * w0.y; a1y += hv.y * w1.y; a1x += hv.z * w2.y; a1y += hv.w * w3.y;
    }
    float a0 = a0x + a0y, a1 = a1x + a1y;
    // reduce-scatter over the quad (VALU DPP, not LDS)
    float keep = odd ? a1 : a0;
    float send = odd ? a0 : a1;
    float v = keep + dpp_mov<DPP_XOR1>(send);
    v += dpp_mov<DPP_XOR2>(v);
    float hnew = tanh_fast(v + xv0);
    h_s[cur ^ 1][jout] = hnew;
    __syncthreads();
    cur ^= 1;
    xv0 = xv1; xv1 = xv2; xv2 = xv3; xv3 = xvn;
  }

  // ---- swap in decoder Wh (same rotated layout) ----
#pragma unroll
  for (int r = 0; r < 8; ++r) {
    const int kb = q * 32 + ((r + 2 * q) & 7) * 4;
#pragma unroll
    for (int c = 0; c < 4; ++c)
      wv[r * 4 + c] = *(const float2*)(&decWh[(kb + c) * HID + jbase]);
  }

  // ======== decoder + fused projection ========
#pragma unroll 2
  for (int t = 0; t < TLEN; ++t) {
    int lab = (t == 0) ? START_TOK : lab_s[t - 1];
    float xv = dxw_s[lab * HID + jout];

    const float4* h4 = (const float4*)(h_s[cur]) + q * 8;
    float a0x = 0, a0y = 0, a1x = 0, a1y = 0;
#pragma unroll
    for (int r = 0; r < 8; ++r) {
      float4 hv = h4[(r + 2 * q) & 7];
      float2 w0 = wv[r * 4 + 0], w1 = wv[r * 4 + 1];
      float2 w2 = wv[r * 4 + 2], w3 = wv[r * 4 + 3];
      a0x += hv.x * w0.x; a0y += hv.y * w1.x; a0x += hv.z * w2.x; a0y += hv.w * w3.x;
      a1x += hv.x * w0.y; a1y += hv.y * w1.y; a1x += hv.z * w2.y; a1y += hv.w * w3.y;
    }
    float a0 = a0x + a0y, a1 = a1x + a1y;
    float keep = odd ? a1 : a0;
    float send = odd ? a0 : a1;
    float v = keep + dpp_mov<DPP_XOR1>(send);
    v += dpp_mov<DPP_XOR2>(v);
    float hnew = tanh_fast(v + xv);
    h_s[cur ^ 1][jout] = hnew;
    __syncthreads();
    cur ^= 1;

    // fused output projection on just-published h_s[cur] (off critical path)
    if (oo < TAGS) {
      const float4* hp = (const float4*)(h_s[cur]) + part * 2;
      float pacc = 0.0f;
#pragma unroll
      for (int s = 0; s < 2; ++s) {
        float4 u = hp[s ^ s0];
        pacc += u.x * wp[s * 4 + 0]; pacc += u.y * wp[s * 4 + 1];
        pacc += u.z * wp[s * 4 + 2]; pacc += u.w * wp[s * 4 + 3];
      }
      pacc += dpp_mov<DPP_XOR1>(pacc);
      pacc += dpp_mov<DPP_XOR2>(pacc);
      pacc += dpp_mov<DPP_HALF_MIRROR>(pacc);
      pacc += dpp_mov<DPP_MIRROR>(pacc);
      if (part == 0) out[(bidx * TLEN + t) * TAGS + oo] = pacc + bo;
    }
  }
}

extern "C" void kernel_launch(void* const* d_in, const int* in_sizes, int n_in,
                              void* d_out, int out_size, void* d_ws, size_t ws_size,
                              hipStream_t stream) {
  const int* inputs   = (const int*)d_in[0];
  const int* labels   = (const int*)d_in[1];
  const float* emb    = (const float*)d_in[2];
  const float* encWx  = (const float*)d_in[3];
  const float* encWh  = (const float*)d_in[4];
  const float* encb   = (const float*)d_in[5];
  const float* demb   = (const float*)d_in[6];
  const float* decWx  = (const float*)d_in[7];
  const float* decWh  = (const float*)d_in[8];
  const float* decb   = (const float*)d_in[9];
  const float* W      = (const float*)d_in[10];
  const float* bo     = (const float*)d_in[11];
  float* out = (float*)d_out;

  float* exw = (float*)d_ws;  // VOCAB*HID floats = 6.22 MB

  exw_kernel<<<(VOCAB + 7) / 8, 128, 0, stream>>>(emb, encWx, encb, exw);
  rnn_kernel<<<BSZ, 256, 0, stream>>>(inputs, labels, exw, encWh,
                                      demb, decWx, decWh, decb, W, bo, out);
}